// Round 4
// baseline (59.505 us; speedup 1.0000x reference)
//
#include <hip/hip_runtime.h>
#include <math.h>

// out[b,i,h,w] = Ar[b,h,i]*cos(2*pi*i*w/128)/128 - Ai[b,h,i]*sin(2*pi*i*w/128)/128
// A = row-DFT of x. Key fact: x real => A[.,128-i] = conj(A[.,i]) and the
// sin factor also flips sign => out[b,128-i,:,:] == out[b,i,:,:] EXACTLY.
// So: compute planes i=0..64 only, store each to both i and 128-i.
//
// Structure: no LDS, no barriers. Each thread keeps its 64-float half-row in
// registers; DFT trig via in-register complex rotation (2 chains of 32, inits
// from sincospif with exact mod-128 reduction). Each wave owns 32 output rows;
// A[h] reaches the store loop via __shfl within the wave. Nontemporal stores
// keep the 268 MB write stream from evicting x out of L2.
//
// Grid: 32 b x 33 groups (g<32: bases {2g,2g+1}; g=32: base 64) = 1056 blocks.

typedef float f32x4 __attribute__((ext_vector_type(4)));

__global__ __launch_bounds__(256) void kspace_v3(const float* __restrict__ x,
                                                 float* __restrict__ out) {
    const int blk  = blockIdx.x;       // 0..1055
    const int b    = blk / 33;
    const int g    = blk % 33;
    const int t    = threadIdx.x;
    const int wv   = t >> 6;           // wave 0..3 -> owns rows wv*32..wv*32+31
    const int lane = t & 63;
    const int hh0  = lane >> 1;        // pair index 0..31
    const int h    = wv * 32 + hh0;    // this thread's DFT row
    const int half = lane & 1;         // which 64-u half of the row

    // ---- load my half-row (64 floats, contiguous 256 B) into registers ----
    const float* xp = x + ((size_t)b * 128 + h) * 128 + half * 64;
    float xs[64];
#pragma unroll
    for (int j = 0; j < 16; ++j) {
        const f32x4 v = ((const f32x4*)xp)[j];
        xs[4 * j + 0] = v.x;
        xs[4 * j + 1] = v.y;
        xs[4 * j + 2] = v.z;
        xs[4 * j + 3] = v.w;
    }

    const int nb = (g < 32) ? 2 : 1;
#pragma unroll 1
    for (int ib = 0; ib < nb; ++ib) {
        const int i = (g < 32) ? (g * 2 + ib) : 64;

        // ---- DFT: A[i][h] = sum_u x[h][u] * e^{-2*pi*I*i*u/128} ----
        // rotation step e^{-I*2*pi*i/128}
        float sstep, cstep;
        sincospif((float)i * (1.0f / 64.0f), &sstep, &cstep);
        const float dc = cstep, ds = -sstep;

        float ar = 0.0f, aiv = 0.0f;
#pragma unroll
        for (int ch = 0; ch < 2; ++ch) {
            const int u0 = half * 64 + ch * 32;
            const int a0 = (i * u0) & 127;            // exact mod-128 phase
            float s0, c0;
            sincospif((float)a0 * (1.0f / 64.0f), &s0, &c0);
            float cr = c0, ci = -s0;                  // e^{-I*theta(u0)}
#pragma unroll
            for (int j2 = 0; j2 < 32; ++j2) {
                const float xv = xs[ch * 32 + j2];
                ar  = fmaf(xv, cr, ar);
                aiv = fmaf(xv, ci, aiv);
                const float ncr = fmaf(cr, dc, -ci * ds);
                ci = fmaf(cr, ds, ci * dc);
                cr = ncr;
            }
        }
        // combine the two half-sums of the pair
        ar  += __shfl_xor(ar, 1);
        aiv += __shfl_xor(aiv, 1);
        ar  *= (1.0f / 128.0f);
        aiv *= (1.0f / 128.0f);

        // ---- per-lane trig for its fixed float4 output column ----
        // lane stores column w = 4*(lane&31)..+3 for all 32 rows of its wave
        const int wbase = (lane & 31) * 4;
        float cwv[4], swv[4];
#pragma unroll
        for (int c = 0; c < 4; ++c) {
            const int k = (i * (wbase + c)) & 127;    // exact mod-128
            sincospif((float)k * (1.0f / 64.0f), &swv[c], &cwv[c]);
        }

        // ---- store plane (b,i) and its exact duplicate (b,128-i) ----
        f32x4* const o1 = (f32x4*)out + (size_t)(b * 128 + i) * 4096;
        f32x4* const o2 = (f32x4*)out + (size_t)(b * 128 + (128 - i)) * 4096;
        const bool dup = (i >= 1 && i <= 63);

#pragma unroll
        for (int j = 0; j < 16; ++j) {
            const int hhl = (lane >> 5) + 2 * j;      // row within wave strip
            const int src = 2 * hhl;                  // lane holding A for it
            const float a  = __shfl(ar,  src);
            const float bb = __shfl(aiv, src);
            f32x4 v;
            v.x = fmaf(a, cwv[0], -bb * swv[0]);
            v.y = fmaf(a, cwv[1], -bb * swv[1]);
            v.z = fmaf(a, cwv[2], -bb * swv[2]);
            v.w = fmaf(a, cwv[3], -bb * swv[3]);
            const int idx = (wv * 32 + hhl) * 32 + (lane & 31);
            __builtin_nontemporal_store(v, &o1[idx]);
            if (dup) __builtin_nontemporal_store(v, &o2[idx]);
        }
    }
}

extern "C" void kernel_launch(void* const* d_in, const int* in_sizes, int n_in,
                              void* d_out, int out_size, void* d_ws, size_t ws_size,
                              hipStream_t stream) {
    const float* x = (const float*)d_in[0];   // (32,1,128,128) f32; mask unused
    float* out = (float*)d_out;               // (32,128,128,128) f32
    kspace_v3<<<dim3(1056), dim3(256), 0, stream>>>(x, out);
}